// Round 1
// baseline (1231.125 us; speedup 1.0000x reference)
//
#include <hip/hip_runtime.h>
#include <hip/hip_bf16.h>

#define DMODEL 1024
#define DI     2048
#define DSTATE 128
#define NH     32
#define HD     64
#define CONVD  2304
#define LSEQ   2048
#define BATCH  2
#define DPROJ  4384
#define DPROJ_PAD 4480
#define EPSV   1e-5f

typedef __attribute__((ext_vector_type(8))) short bf16x8;
typedef __attribute__((ext_vector_type(4))) float f32x4;

// ---------------- conversion kernels ----------------

__global__ void f32_to_bf16_kernel(const float* __restrict__ in,
                                   __hip_bfloat16* __restrict__ out, int n4) {
  int i = blockIdx.x * 256 + threadIdx.x;
  if (i >= n4) return;
  float4 v = reinterpret_cast<const float4*>(in)[i];
  union { ushort4 u; __hip_bfloat16 h[4]; } cv;
  cv.h[0] = __float2bfloat16(v.x);
  cv.h[1] = __float2bfloat16(v.y);
  cv.h[2] = __float2bfloat16(v.z);
  cv.h[3] = __float2bfloat16(v.w);
  reinterpret_cast<ushort4*>(out)[i] = cv.u;
}

// out[n][k] = in[k][n] as bf16; zero-fill for n in [C, Cpad)
__global__ void transpose_f32_bf16(const float* __restrict__ in,
                                   __hip_bfloat16* __restrict__ out,
                                   int R, int C, int Cpad) {
  __shared__ float tile[32][33];
  int n0 = blockIdx.x * 32, k0 = blockIdx.y * 32;
  int tx = threadIdx.x, ty = threadIdx.y;  // (32,8)
#pragma unroll
  for (int j = 0; j < 32; j += 8) {
    int k = k0 + ty + j, n = n0 + tx;
    tile[ty + j][tx] = (n < C) ? in[(size_t)k * C + n] : 0.f;
  }
  __syncthreads();
#pragma unroll
  for (int j = 0; j < 32; j += 8) {
    int n = n0 + ty + j, k = k0 + tx;
    if (n < Cpad) out[(size_t)n * R + k] = __float2bfloat16(tile[tx][ty + j]);
  }
}

// ---------------- GEMM: C(MxN,f32) = A(MxK,bf16) * Bt(NxK,bf16)^T ----------------
// m97 structure: 128x128 tile, BK=32, 4 waves each computing 64x64 via 4x4 16x16x32 frags.

__global__ __launch_bounds__(256, 2)
void gemm_bt_kernel(const __hip_bfloat16* __restrict__ A,
                    const __hip_bfloat16* __restrict__ Bt,
                    float* __restrict__ C,
                    int M, int N, int K, int NT) {
  __shared__ __hip_bfloat16 smA[128 * 32];
  __shared__ __hip_bfloat16 smB[128 * 32];
  const int bid = blockIdx.x;
  const int bm = (bid / NT) * 128;
  const int bn = (bid % NT) * 128;
  const int t = threadIdx.x;
  const int w = t >> 6, lane = t & 63;
  const int wr = (w >> 1) * 64, wc = (w & 1) * 64;

  f32x4 acc[4][4];
#pragma unroll
  for (int m = 0; m < 4; ++m)
#pragma unroll
    for (int n = 0; n < 4; ++n) acc[m][n] = (f32x4){0.f, 0.f, 0.f, 0.f};

  const int rl = lane >> 2;         // 0..15 row within wave's 16-row staging slice
  const int kof = (lane & 3) * 8;   // 0,8,16,24 bf16 within the 32-wide K slice
  const size_t aBase0 = (size_t)(bm + w * 16 + rl) * K + kof;
  const size_t aBase1 = aBase0 + (size_t)64 * K;
  const size_t bBase0 = (size_t)(bn + w * 16 + rl) * K + kof;
  const size_t bBase1 = bBase0 + (size_t)64 * K;
  __hip_bfloat16* ldsA0 = smA + w * 512;
  __hip_bfloat16* ldsA1 = smA + w * 512 + 64 * 32;
  __hip_bfloat16* ldsB0 = smB + w * 512;
  __hip_bfloat16* ldsB1 = smB + w * 512 + 64 * 32;

  const int fr = lane & 15;
  const int fk = (lane >> 4) * 8;

  for (int k0 = 0; k0 < K; k0 += 32) {
    __builtin_amdgcn_global_load_lds((const __attribute__((address_space(1))) void*)(A + aBase0 + k0),
                                     (__attribute__((address_space(3))) void*)ldsA0, 16, 0, 0);
    __builtin_amdgcn_global_load_lds((const __attribute__((address_space(1))) void*)(A + aBase1 + k0),
                                     (__attribute__((address_space(3))) void*)ldsA1, 16, 0, 0);
    __builtin_amdgcn_global_load_lds((const __attribute__((address_space(1))) void*)(Bt + bBase0 + k0),
                                     (__attribute__((address_space(3))) void*)ldsB0, 16, 0, 0);
    __builtin_amdgcn_global_load_lds((const __attribute__((address_space(1))) void*)(Bt + bBase1 + k0),
                                     (__attribute__((address_space(3))) void*)ldsB1, 16, 0, 0);
    __syncthreads();
    bf16x8 af[4], bfv[4];
#pragma unroll
    for (int m = 0; m < 4; ++m)
      af[m] = *reinterpret_cast<const bf16x8*>(smA + (wr + m * 16 + fr) * 32 + fk);
#pragma unroll
    for (int n = 0; n < 4; ++n)
      bfv[n] = *reinterpret_cast<const bf16x8*>(smB + (wc + n * 16 + fr) * 32 + fk);
#pragma unroll
    for (int m = 0; m < 4; ++m)
#pragma unroll
      for (int n = 0; n < 4; ++n)
        acc[m][n] = __builtin_amdgcn_mfma_f32_16x16x32_bf16(af[m], bfv[n], acc[m][n], 0, 0, 0);
    __syncthreads();
  }

  const int r4 = (lane >> 4) * 4;
  const int cn = lane & 15;
#pragma unroll
  for (int m = 0; m < 4; ++m)
#pragma unroll
    for (int n = 0; n < 4; ++n) {
      int row = bm + wr + m * 16 + r4;
      int col = bn + wc + n * 16 + cn;
      float* cp = C + (size_t)row * N + col;
#pragma unroll
      for (int j = 0; j < 4; ++j) cp[(size_t)j * N] = acc[m][n][j];
    }
}

// ---------------- dt / decay precompute ----------------

__global__ void dtdecay_kernel(const float* __restrict__ zx, const float* __restrict__ dt_bias,
                               const float* __restrict__ A_log,
                               float* __restrict__ dtb, float* __restrict__ decb) {
  int idx = blockIdx.x * 256 + threadIdx.x;
  if (idx >= BATCH * LSEQ * NH) return;
  int h = idx & 31;
  int bl = idx >> 5;
  float v = zx[(size_t)bl * DPROJ_PAD + (DI + CONVD) + h] + dt_bias[h];
  float dt = (v > 20.f) ? v : log1pf(expf(v));
  float dec = expf(-expf(A_log[h]) * dt);
  dtb[idx] = dt;
  decb[idx] = dec;
}

// ---------------- causal depthwise conv + silu ----------------

__global__ void conv_silu_kernel(const float* __restrict__ zx, const float* __restrict__ cw,
                                 const float* __restrict__ cb, float* __restrict__ xbc) {
  int idx = blockIdx.x * 256 + threadIdx.x;
  if (idx >= BATCH * LSEQ * CONVD) return;
  int c = idx % CONVD;
  int bl = idx / CONVD;
  int l = bl % LSEQ;
  int b = bl / LSEQ;
  const float* src = zx + (size_t)b * LSEQ * DPROJ_PAD + DI + c;
  float acc = cb[c];
  float4 wv = *reinterpret_cast<const float4*>(cw + c * 4);
  if (l >= 3) acc += wv.x * src[(size_t)(l - 3) * DPROJ_PAD];
  if (l >= 2) acc += wv.y * src[(size_t)(l - 2) * DPROJ_PAD];
  if (l >= 1) acc += wv.z * src[(size_t)(l - 1) * DPROJ_PAD];
  acc += wv.w * src[(size_t)l * DPROJ_PAD];
  xbc[idx] = acc / (1.f + expf(-acc));
}

// ---------------- sequential selective-state scan ----------------
// one wave per (b,h,p) row; 64 lanes x 2 state elements (n-dim 128)

__global__ __launch_bounds__(256)
void scan_kernel(const float* __restrict__ xbc, const float* __restrict__ dtb,
                 const float* __restrict__ decb, const float* __restrict__ Dparm,
                 float* __restrict__ y) {
  int w = threadIdx.x >> 6, lane = threadIdx.x & 63;
  int bid = blockIdx.x;            // 0..1023
  int pg = bid & 15;
  int bh = bid >> 4;
  int h = bh & 31;
  int b = bh >> 5;
  int p = pg * 4 + w;

  const float* xc = xbc + (size_t)b * LSEQ * CONVD;
  const float* xp = xc + h * HD + p;
  const float* Bp = xc + DI + lane * 2;
  const float* Cp = xc + DI + DSTATE + lane * 2;
  const float* dtp = dtb + (size_t)b * LSEQ * NH + h;
  const float* dcp = decb + (size_t)b * LSEQ * NH + h;
  float* yp = y + (size_t)b * LSEQ * DI + h * HD + p;
  float Dh = Dparm[h];

  float h0 = 0.f, h1 = 0.f;
  for (int l = 0; l < LSEQ; ++l) {
    float2 Bv = *reinterpret_cast<const float2*>(Bp);
    float2 Cv = *reinterpret_cast<const float2*>(Cp);
    float dec = *dcp;
    float dts = *dtp;
    float xv = *xp;
    float s = dts * xv;
    h0 = fmaf(h0, dec, s * Bv.x);
    h1 = fmaf(h1, dec, s * Bv.y);
    float pp = fmaf(h1, Cv.y, h0 * Cv.x);
#pragma unroll
    for (int off = 32; off; off >>= 1) pp += __shfl_down(pp, off);
    if (lane == 0) yp[0] = pp + Dh * xv;
    Bp += CONVD; Cp += CONVD; xp += CONVD;
    dtp += NH; dcp += NH; yp += DI;
  }
}

// ---------------- gating + RMS norm -> bf16 ----------------

__global__ __launch_bounds__(256)
void gate_rms_kernel(const float* __restrict__ y, const float* __restrict__ zx,
                     const float* __restrict__ nw, __hip_bfloat16* __restrict__ g) {
  int row = blockIdx.x;
  int t = threadIdx.x;
  const float* yr = y + (size_t)row * DI;
  const float* zr = zx + (size_t)row * DPROJ_PAD;
  float v[8];
  float ss = 0.f;
#pragma unroll
  for (int j = 0; j < 8; ++j) {
    int c = j * 256 + t;
    float z = zr[c];
    float vv = yr[c] * (z / (1.f + expf(-z)));
    v[j] = vv;
    ss += vv * vv;
  }
#pragma unroll
  for (int off = 32; off; off >>= 1) ss += __shfl_down(ss, off);
  __shared__ float red[4];
  if ((t & 63) == 0) red[t >> 6] = ss;
  __syncthreads();
  float tot = red[0] + red[1] + red[2] + red[3];
  float rstd = rsqrtf(tot * (1.f / DI) + EPSV);
#pragma unroll
  for (int j = 0; j < 8; ++j) {
    int c = j * 256 + t;
    g[(size_t)row * DI + c] = __float2bfloat16(v[j] * rstd * nw[c]);
  }
}

// ---------------- final RMS + residual ----------------

__global__ __launch_bounds__(256)
void final_rms_add(const float* __restrict__ o1, const float* __restrict__ x,
                   float* __restrict__ out) {
  int row = blockIdx.x;
  int t = threadIdx.x;
  const float* orow = o1 + (size_t)row * DMODEL;
  float v[4];
  float ss = 0.f;
#pragma unroll
  for (int j = 0; j < 4; ++j) {
    int c = j * 256 + t;
    float o = orow[c];
    v[j] = o;
    ss += o * o;
  }
#pragma unroll
  for (int off = 32; off; off >>= 1) ss += __shfl_down(ss, off);
  __shared__ float red[4];
  if ((t & 63) == 0) red[t >> 6] = ss;
  __syncthreads();
  float tot = red[0] + red[1] + red[2] + red[3];
  float rstd = rsqrtf(tot * (1.f / DMODEL) + EPSV);
#pragma unroll
  for (int j = 0; j < 4; ++j) {
    int c = j * 256 + t;
    out[(size_t)row * DMODEL + c] = v[j] * rstd + x[(size_t)row * DMODEL + c];
  }
}

// ---------------- launch ----------------

extern "C" void kernel_launch(void* const* d_in, const int* in_sizes, int n_in,
                              void* d_out, int out_size, void* d_ws, size_t ws_size,
                              hipStream_t stream) {
  const float* x       = (const float*)d_in[0];
  const float* W_in    = (const float*)d_in[1];
  const float* conv_w  = (const float*)d_in[2];
  const float* conv_b  = (const float*)d_in[3];
  const float* dt_bias = (const float*)d_in[4];
  const float* A_log   = (const float*)d_in[5];
  const float* Dp      = (const float*)d_in[6];
  const float* norm_w  = (const float*)d_in[7];
  const float* W_out   = (const float*)d_in[8];
  float* out = (float*)d_out;

  // workspace layout (floats), total ~160 MB
  float* zx   = (float*)d_ws;                 // 4096 x 4480            = 18,350,080
  float* xbc  = zx + (size_t)18350080;        // 4096 x 2304            =  9,437,184
  float* ybuf = xbc + (size_t)9437184;        // 4096 x 2048            =  8,388,608
  float* dtb  = ybuf + (size_t)8388608;       // 131072
  float* decb = dtb + (size_t)131072;         // 131072
  __hip_bfloat16* xbf   = (__hip_bfloat16*)(decb + 131072);  // 4096x1024
  __hip_bfloat16* wtin  = xbf + (size_t)4194304;             // 4480x1024
  __hip_bfloat16* wtout = wtin + (size_t)4587520;            // 1024x2048
  __hip_bfloat16* gbf = xbf;   // overlay: x_bf/wtin dead after GEMM1
  float* o1 = xbc;             // overlay: xbc dead after scan

  f32_to_bf16_kernel<<<4096, 256, 0, stream>>>(x, xbf, 1048576);
  transpose_f32_bf16<<<dim3(140, 32), dim3(32, 8), 0, stream>>>(W_in, wtin, 1024, 4384, 4480);
  transpose_f32_bf16<<<dim3(32, 64), dim3(32, 8), 0, stream>>>(W_out, wtout, 2048, 1024, 1024);

  gemm_bt_kernel<<<1120, 256, 0, stream>>>(xbf, wtin, zx, 4096, 4480, 1024, 35);

  dtdecay_kernel<<<512, 256, 0, stream>>>(zx, dt_bias, A_log, dtb, decb);
  conv_silu_kernel<<<36864, 256, 0, stream>>>(zx, conv_w, conv_b, xbc);
  scan_kernel<<<1024, 256, 0, stream>>>(xbc, dtb, decb, Dp, ybuf);
  gate_rms_kernel<<<4096, 256, 0, stream>>>(ybuf, zx, norm_w, gbf);

  gemm_bt_kernel<<<256, 256, 0, stream>>>(gbf, wtout, o1, 4096, 1024, 2048, 8);

  final_rms_add<<<4096, 256, 0, stream>>>(o1, x, out);
}

// Round 2
// 416.185 us; speedup vs baseline: 2.9581x; 2.9581x over previous
//
#include <hip/hip_runtime.h>
#include <hip/hip_bf16.h>

#define DMODEL 1024
#define DI     2048
#define DSTATE 128
#define NH     32
#define HD     64
#define CONVD  2304
#define LSEQ   2048
#define BATCH  2
#define DPROJ  4384
#define DPROJ_PAD 4480
#define EPSV   1e-5f
#define QCH    128
#define NCH    16

typedef __attribute__((ext_vector_type(8))) short bf16x8;
typedef __attribute__((ext_vector_type(4))) float f32x4;

// ---------------- conversion kernels ----------------

__global__ void f32_to_bf16_kernel(const float* __restrict__ in,
                                   __hip_bfloat16* __restrict__ out, int n4) {
  int i = blockIdx.x * 256 + threadIdx.x;
  if (i >= n4) return;
  float4 v = reinterpret_cast<const float4*>(in)[i];
  union { ushort4 u; __hip_bfloat16 h[4]; } cv;
  cv.h[0] = __float2bfloat16(v.x);
  cv.h[1] = __float2bfloat16(v.y);
  cv.h[2] = __float2bfloat16(v.z);
  cv.h[3] = __float2bfloat16(v.w);
  reinterpret_cast<ushort4*>(out)[i] = cv.u;
}

// out[n][k] = in[k][n] as bf16; zero-fill for n in [C, Cpad)
__global__ void transpose_f32_bf16(const float* __restrict__ in,
                                   __hip_bfloat16* __restrict__ out,
                                   int R, int C, int Cpad) {
  __shared__ float tile[32][33];
  int n0 = blockIdx.x * 32, k0 = blockIdx.y * 32;
  int tx = threadIdx.x, ty = threadIdx.y;  // (32,8)
#pragma unroll
  for (int j = 0; j < 32; j += 8) {
    int k = k0 + ty + j, n = n0 + tx;
    tile[ty + j][tx] = (n < C) ? in[(size_t)k * C + n] : 0.f;
  }
  __syncthreads();
#pragma unroll
  for (int j = 0; j < 32; j += 8) {
    int n = n0 + ty + j, k = k0 + tx;
    if (n < Cpad) out[(size_t)n * R + k] = __float2bfloat16(tile[tx][ty + j]);
  }
}

// ---------------- GEMM: C(MxN,f32) = A(MxK,bf16) * Bt(NxK,bf16)^T ----------------

__global__ __launch_bounds__(256, 2)
void gemm_bt_kernel(const __hip_bfloat16* __restrict__ A,
                    const __hip_bfloat16* __restrict__ Bt,
                    float* __restrict__ C,
                    int M, int N, int K, int NT) {
  __shared__ __hip_bfloat16 smA[128 * 32];
  __shared__ __hip_bfloat16 smB[128 * 32];
  const int bid = blockIdx.x;
  const int bm = (bid / NT) * 128;
  const int bn = (bid % NT) * 128;
  const int t = threadIdx.x;
  const int w = t >> 6, lane = t & 63;
  const int wr = (w >> 1) * 64, wc = (w & 1) * 64;

  f32x4 acc[4][4];
#pragma unroll
  for (int m = 0; m < 4; ++m)
#pragma unroll
    for (int n = 0; n < 4; ++n) acc[m][n] = (f32x4){0.f, 0.f, 0.f, 0.f};

  const int rl = lane >> 2;
  const int kof = (lane & 3) * 8;
  const size_t aBase0 = (size_t)(bm + w * 16 + rl) * K + kof;
  const size_t aBase1 = aBase0 + (size_t)64 * K;
  const size_t bBase0 = (size_t)(bn + w * 16 + rl) * K + kof;
  const size_t bBase1 = bBase0 + (size_t)64 * K;
  __hip_bfloat16* ldsA0 = smA + w * 512;
  __hip_bfloat16* ldsA1 = smA + w * 512 + 64 * 32;
  __hip_bfloat16* ldsB0 = smB + w * 512;
  __hip_bfloat16* ldsB1 = smB + w * 512 + 64 * 32;

  const int fr = lane & 15;
  const int fk = (lane >> 4) * 8;

  for (int k0 = 0; k0 < K; k0 += 32) {
    __builtin_amdgcn_global_load_lds((const __attribute__((address_space(1))) void*)(A + aBase0 + k0),
                                     (__attribute__((address_space(3))) void*)ldsA0, 16, 0, 0);
    __builtin_amdgcn_global_load_lds((const __attribute__((address_space(1))) void*)(A + aBase1 + k0),
                                     (__attribute__((address_space(3))) void*)ldsA1, 16, 0, 0);
    __builtin_amdgcn_global_load_lds((const __attribute__((address_space(1))) void*)(Bt + bBase0 + k0),
                                     (__attribute__((address_space(3))) void*)ldsB0, 16, 0, 0);
    __builtin_amdgcn_global_load_lds((const __attribute__((address_space(1))) void*)(Bt + bBase1 + k0),
                                     (__attribute__((address_space(3))) void*)ldsB1, 16, 0, 0);
    __syncthreads();
    bf16x8 af[4], bfv[4];
#pragma unroll
    for (int m = 0; m < 4; ++m)
      af[m] = *reinterpret_cast<const bf16x8*>(smA + (wr + m * 16 + fr) * 32 + fk);
#pragma unroll
    for (int n = 0; n < 4; ++n)
      bfv[n] = *reinterpret_cast<const bf16x8*>(smB + (wc + n * 16 + fr) * 32 + fk);
#pragma unroll
    for (int m = 0; m < 4; ++m)
#pragma unroll
      for (int n = 0; n < 4; ++n)
        acc[m][n] = __builtin_amdgcn_mfma_f32_16x16x32_bf16(af[m], bfv[n], acc[m][n], 0, 0, 0);
    __syncthreads();
  }

  const int r4 = (lane >> 4) * 4;
  const int cn = lane & 15;
#pragma unroll
  for (int m = 0; m < 4; ++m)
#pragma unroll
    for (int n = 0; n < 4; ++n) {
      int row = bm + wr + m * 16 + r4;
      int col = bn + wc + n * 16 + cn;
      float* cp = C + (size_t)row * N + col;
#pragma unroll
      for (int j = 0; j < 4; ++j) cp[(size_t)j * N] = acc[m][n][j];
    }
}

// ---------------- dt / decay precompute ----------------

__global__ void dtdecay_kernel(const float* __restrict__ zx, const float* __restrict__ dt_bias,
                               const float* __restrict__ A_log,
                               float* __restrict__ dtb, float* __restrict__ decb) {
  int idx = blockIdx.x * 256 + threadIdx.x;
  if (idx >= BATCH * LSEQ * NH) return;
  int h = idx & 31;
  int bl = idx >> 5;
  float v = zx[(size_t)bl * DPROJ_PAD + (DI + CONVD) + h] + dt_bias[h];
  float dt = (v > 20.f) ? v : log1pf(expf(v));
  float dec = expf(-expf(A_log[h]) * dt);
  dtb[idx] = dt;
  decb[idx] = dec;
}

// ---------------- causal depthwise conv + silu ----------------

__global__ void conv_silu_kernel(const float* __restrict__ zx, const float* __restrict__ cw,
                                 const float* __restrict__ cb, float* __restrict__ xbc) {
  int idx = blockIdx.x * 256 + threadIdx.x;
  if (idx >= BATCH * LSEQ * CONVD) return;
  int c = idx % CONVD;
  int bl = idx / CONVD;
  int l = bl % LSEQ;
  int b = bl / LSEQ;
  const float* src = zx + (size_t)b * LSEQ * DPROJ_PAD + DI + c;
  float acc = cb[c];
  float4 wv = *reinterpret_cast<const float4*>(cw + c * 4);
  if (l >= 3) acc += wv.x * src[(size_t)(l - 3) * DPROJ_PAD];
  if (l >= 2) acc += wv.y * src[(size_t)(l - 2) * DPROJ_PAD];
  if (l >= 1) acc += wv.z * src[(size_t)(l - 1) * DPROJ_PAD];
  acc += wv.w * src[(size_t)l * DPROJ_PAD];
  xbc[idx] = acc / (1.f + expf(-acc));
}

// ---------------- chunked scan, pass 1: local scans ----------------
// wg = (b,h,c); thread: wave w owns p = w*16+(lane&15); ng = lane>>4 owns 32 n.
// h[p][n-slice] lives in 32 VGPRs. B/C staged via LDS, broadcast-read with
// per-ng rotation so 4 lane-groups hit 4 distinct bank-quads (conflict-free).

__global__ __launch_bounds__(256)
void ssd_local_kernel(const float* __restrict__ xbc, const float* __restrict__ dtb,
                      const float* __restrict__ decb, const float* __restrict__ Dparm,
                      float* __restrict__ y, __hip_bfloat16* __restrict__ sbuf,
                      float* __restrict__ pbuf) {
  __shared__ float bc[2][256];
  int bid = blockIdx.x;
  int c = bid & (NCH - 1);
  int h = (bid >> 4) & 31;
  int b = bid >> 9;
  int tid = threadIdx.x;
  int w = tid >> 6, l = tid & 63;
  int pl = l & 15, ng = l >> 4;
  int p = w * 16 + pl;
  int t0 = c * QCH;
  int nbase = ng * 32;

  const float* xc = xbc + (size_t)b * LSEQ * CONVD;
  float Dh = Dparm[h];

  float hreg[32];
#pragma unroll
  for (int i = 0; i < 32; ++i) hreg[i] = 0.f;

  // prologue: stage B,C for t0
  bc[0][tid] = xc[(size_t)t0 * CONVD + DI + tid];

  float pc = 1.f;
  for (int tt = 0; tt < QCH; ++tt) {
    int t = t0 + tt;
    __syncthreads();
    int cur = tt & 1;
    float Bf[32], Cf[32];
#pragma unroll
    for (int j = 0; j < 8; ++j) {
      int off = nbase + (((j + 2 * ng) & 7) << 2);
      *reinterpret_cast<float4*>(&Bf[j * 4]) = *reinterpret_cast<const float4*>(&bc[cur][off]);
      *reinterpret_cast<float4*>(&Cf[j * 4]) = *reinterpret_cast<const float4*>(&bc[cur][128 + off]);
    }
    if (tt + 1 < QCH)
      bc[cur ^ 1][tid] = xc[(size_t)(t + 1) * CONVD + DI + tid];
    float dec = decb[((size_t)b * LSEQ + t) * NH + h];
    float dts = dtb[((size_t)b * LSEQ + t) * NH + h];
    float xv = xc[(size_t)t * CONVD + h * HD + p];
    float s = dts * xv;
    float yv0 = 0.f, yv1 = 0.f, yv2 = 0.f, yv3 = 0.f;
#pragma unroll
    for (int j = 0; j < 8; ++j) {
      float h0 = fmaf(hreg[j * 4 + 0], dec, s * Bf[j * 4 + 0]);
      float h1 = fmaf(hreg[j * 4 + 1], dec, s * Bf[j * 4 + 1]);
      float h2 = fmaf(hreg[j * 4 + 2], dec, s * Bf[j * 4 + 2]);
      float h3 = fmaf(hreg[j * 4 + 3], dec, s * Bf[j * 4 + 3]);
      hreg[j * 4 + 0] = h0; hreg[j * 4 + 1] = h1;
      hreg[j * 4 + 2] = h2; hreg[j * 4 + 3] = h3;
      yv0 = fmaf(h0, Cf[j * 4 + 0], yv0);
      yv1 = fmaf(h1, Cf[j * 4 + 1], yv1);
      yv2 = fmaf(h2, Cf[j * 4 + 2], yv2);
      yv3 = fmaf(h3, Cf[j * 4 + 3], yv3);
    }
    float yv = (yv0 + yv1) + (yv2 + yv3);
    yv += __shfl_xor(yv, 16);
    yv += __shfl_xor(yv, 32);
    pc *= dec;
    if (ng == 0)
      y[((size_t)b * LSEQ + t) * DI + h * HD + p] = yv + Dh * xv;
  }
  // store local end-state at true (swizzled) n positions: layout sbuf[bid][n][p]
  __hip_bfloat16* sp = sbuf + (size_t)bid * 8192;
#pragma unroll
  for (int j = 0; j < 8; ++j) {
    int n4 = nbase + (((j + 2 * ng) & 7) << 2);
#pragma unroll
    for (int e = 0; e < 4; ++e)
      sp[(n4 + e) * 64 + p] = __float2bfloat16(hreg[j * 4 + e]);
  }
  if (tid == 0) pbuf[bid] = pc;
}

// ---------------- chunked scan, pass 2: propagate chunk states ----------------
// in-place: sbuf[c] (local end state S_c) -> h_start_c

__global__ void ssd_prop_kernel(__hip_bfloat16* __restrict__ sbuf,
                                const float* __restrict__ pbuf) {
  int idx = blockIdx.x * 256 + threadIdx.x;   // 64 * 8192
  int bh = idx >> 13;
  int e = idx & 8191;
  __hip_bfloat16* base = sbuf + (size_t)bh * NCH * 8192 + e;
  const float* pb = pbuf + bh * NCH;
  float hs = 0.f;
  for (int cc = 0; cc < NCH; ++cc) {
    float sc = __bfloat162float(base[(size_t)cc * 8192]);
    base[(size_t)cc * 8192] = __float2bfloat16(hs);
    hs = fmaf(hs, pb[cc], sc);
  }
}

// ---------------- chunked scan, pass 3: cross-chunk correction ----------------
// y[t] += cumdec(t) * (C_t . h_start_c[p,:])

__global__ __launch_bounds__(256)
void ssd_corr_kernel(const float* __restrict__ xbc, const float* __restrict__ decb,
                     const __hip_bfloat16* __restrict__ sbuf, float* __restrict__ y) {
  int bid = blockIdx.x;
  int c = bid & (NCH - 1);
  if (c == 0) return;  // h_start = 0, no correction (block-uniform exit)
  __shared__ float cst[2][128];
  int h = (bid >> 4) & 31;
  int b = bid >> 9;
  int tid = threadIdx.x;
  int w = tid >> 6, l = tid & 63;
  int pl = l & 15, ng = l >> 4;
  int p = w * 16 + pl;
  int t0 = c * QCH;
  int nbase = ng * 32;

  const float* xc = xbc + (size_t)b * LSEQ * CONVD;
  const __hip_bfloat16* sp = sbuf + (size_t)bid * 8192;
  float hs[32];
#pragma unroll
  for (int j = 0; j < 8; ++j) {
    int n4 = nbase + (((j + 2 * ng) & 7) << 2);
#pragma unroll
    for (int e = 0; e < 4; ++e)
      hs[j * 4 + e] = __bfloat162float(sp[(n4 + e) * 64 + p]);
  }

  if (tid < 128) cst[0][tid] = xc[(size_t)t0 * CONVD + DI + DSTATE + tid];
  float cum = 1.f;
  for (int tt = 0; tt < QCH; ++tt) {
    int t = t0 + tt;
    __syncthreads();
    int cur = tt & 1;
    float Cf[32];
#pragma unroll
    for (int j = 0; j < 8; ++j) {
      int off = nbase + (((j + 2 * ng) & 7) << 2);
      *reinterpret_cast<float4*>(&Cf[j * 4]) = *reinterpret_cast<const float4*>(&cst[cur][off]);
    }
    if (tt + 1 < QCH && tid < 128)
      cst[cur ^ 1][tid] = xc[(size_t)(t + 1) * CONVD + DI + DSTATE + tid];
    float dec = decb[((size_t)b * LSEQ + t) * NH + h];
    cum *= dec;
    float yv0 = 0.f, yv1 = 0.f, yv2 = 0.f, yv3 = 0.f;
#pragma unroll
    for (int j = 0; j < 8; ++j) {
      yv0 = fmaf(hs[j * 4 + 0], Cf[j * 4 + 0], yv0);
      yv1 = fmaf(hs[j * 4 + 1], Cf[j * 4 + 1], yv1);
      yv2 = fmaf(hs[j * 4 + 2], Cf[j * 4 + 2], yv2);
      yv3 = fmaf(hs[j * 4 + 3], Cf[j * 4 + 3], yv3);
    }
    float yv = (yv0 + yv1) + (yv2 + yv3);
    yv += __shfl_xor(yv, 16);
    yv += __shfl_xor(yv, 32);
    if (ng == 0) {
      size_t yi = ((size_t)b * LSEQ + t) * DI + h * HD + p;
      y[yi] += cum * yv;
    }
  }
}

// ---------------- gating + RMS norm -> bf16 ----------------

__global__ __launch_bounds__(256)
void gate_rms_kernel(const float* __restrict__ y, const float* __restrict__ zx,
                     const float* __restrict__ nw, __hip_bfloat16* __restrict__ g) {
  int row = blockIdx.x;
  int t = threadIdx.x;
  const float* yr = y + (size_t)row * DI;
  const float* zr = zx + (size_t)row * DPROJ_PAD;
  float v[8];
  float ss = 0.f;
#pragma unroll
  for (int j = 0; j < 8; ++j) {
    int c = j * 256 + t;
    float z = zr[c];
    float vv = yr[c] * (z / (1.f + expf(-z)));
    v[j] = vv;
    ss += vv * vv;
  }
#pragma unroll
  for (int off = 32; off; off >>= 1) ss += __shfl_down(ss, off);
  __shared__ float red[4];
  if ((t & 63) == 0) red[t >> 6] = ss;
  __syncthreads();
  float tot = red[0] + red[1] + red[2] + red[3];
  float rstd = rsqrtf(tot * (1.f / DI) + EPSV);
#pragma unroll
  for (int j = 0; j < 8; ++j) {
    int c = j * 256 + t;
    g[(size_t)row * DI + c] = __float2bfloat16(v[j] * rstd * nw[c]);
  }
}

// ---------------- final RMS + residual ----------------

__global__ __launch_bounds__(256)
void final_rms_add(const float* __restrict__ o1, const float* __restrict__ x,
                   float* __restrict__ out) {
  int row = blockIdx.x;
  int t = threadIdx.x;
  const float* orow = o1 + (size_t)row * DMODEL;
  float v[4];
  float ss = 0.f;
#pragma unroll
  for (int j = 0; j < 4; ++j) {
    int c = j * 256 + t;
    float o = orow[c];
    v[j] = o;
    ss += o * o;
  }
#pragma unroll
  for (int off = 32; off; off >>= 1) ss += __shfl_down(ss, off);
  __shared__ float red[4];
  if ((t & 63) == 0) red[t >> 6] = ss;
  __syncthreads();
  float tot = red[0] + red[1] + red[2] + red[3];
  float rstd = rsqrtf(tot * (1.f / DMODEL) + EPSV);
#pragma unroll
  for (int j = 0; j < 4; ++j) {
    int c = j * 256 + t;
    out[(size_t)row * DMODEL + c] = v[j] * rstd + x[(size_t)row * DMODEL + c];
  }
}

// ---------------- launch ----------------

extern "C" void kernel_launch(void* const* d_in, const int* in_sizes, int n_in,
                              void* d_out, int out_size, void* d_ws, size_t ws_size,
                              hipStream_t stream) {
  const float* x       = (const float*)d_in[0];
  const float* W_in    = (const float*)d_in[1];
  const float* conv_w  = (const float*)d_in[2];
  const float* conv_b  = (const float*)d_in[3];
  const float* dt_bias = (const float*)d_in[4];
  const float* A_log   = (const float*)d_in[5];
  const float* Dp      = (const float*)d_in[6];
  const float* norm_w  = (const float*)d_in[7];
  const float* W_out   = (const float*)d_in[8];
  float* out = (float*)d_out;

  // workspace layout (same footprint as the passing round-1 layout)
  float* zx   = (float*)d_ws;                 // 4096 x 4480
  float* xbc  = zx + (size_t)18350080;        // 4096 x 2304
  float* ybuf = xbc + (size_t)9437184;        // 4096 x 2048
  float* dtb  = ybuf + (size_t)8388608;       // 131072
  float* decb = dtb + (size_t)131072;         // 131072
  __hip_bfloat16* xbf   = (__hip_bfloat16*)(decb + 131072);  // 4096x1024
  __hip_bfloat16* wtin  = xbf + (size_t)4194304;             // 4480x1024
  __hip_bfloat16* wtout = wtin + (size_t)4587520;            // 1024x2048
  float* pbuf = (float*)(wtout + (size_t)2097152);           // 1024 floats
  __hip_bfloat16* sbuf = xbf;  // overlay: xbf/wtin dead after GEMM1 (needs 8,388,608 bf16 <= 8,781,824)
  __hip_bfloat16* gbf = xbf;   // overlay: sbuf dead after ssd_corr
  float* o1 = xbc;             // overlay: xbc dead after ssd_corr

  f32_to_bf16_kernel<<<4096, 256, 0, stream>>>(x, xbf, 1048576);
  transpose_f32_bf16<<<dim3(140, 32), dim3(32, 8), 0, stream>>>(W_in, wtin, 1024, 4384, 4480);
  transpose_f32_bf16<<<dim3(32, 64), dim3(32, 8), 0, stream>>>(W_out, wtout, 2048, 1024, 1024);

  gemm_bt_kernel<<<1120, 256, 0, stream>>>(xbf, wtin, zx, 4096, 4480, 1024, 35);

  dtdecay_kernel<<<512, 256, 0, stream>>>(zx, dt_bias, A_log, dtb, decb);
  conv_silu_kernel<<<36864, 256, 0, stream>>>(zx, conv_w, conv_b, xbc);

  ssd_local_kernel<<<1024, 256, 0, stream>>>(xbc, dtb, decb, Dp, ybuf, sbuf, pbuf);
  ssd_prop_kernel<<<2048, 256, 0, stream>>>(sbuf, pbuf);
  ssd_corr_kernel<<<1024, 256, 0, stream>>>(xbc, decb, sbuf, ybuf);

  gate_rms_kernel<<<4096, 256, 0, stream>>>(ybuf, zx, norm_w, gbf);

  gemm_bt_kernel<<<256, 256, 0, stream>>>(gbf, wtout, o1, 4096, 1024, 2048, 8);

  final_rms_add<<<4096, 256, 0, stream>>>(o1, x, out);
}

// Round 4
// 396.321 us; speedup vs baseline: 3.1064x; 1.0501x over previous
//
#include <hip/hip_runtime.h>
#include <hip/hip_bf16.h>

#define DMODEL 1024
#define DI     2048
#define DSTATE 128
#define NH     32
#define HD     64
#define CONVD  2304
#define LSEQ   2048
#define BATCH  2
#define DPROJ  4384
#define DPROJ_PAD 4480
#define EPSV   1e-5f
#define QCH    128
#define NCH    16
#define TB     8

typedef __attribute__((ext_vector_type(8))) short bf16x8;
typedef __attribute__((ext_vector_type(4))) float f32x4;

// ---------------- conversion kernels ----------------

__global__ void f32_to_bf16_kernel(const float* __restrict__ in,
                                   __hip_bfloat16* __restrict__ out, int n4) {
  int i = blockIdx.x * 256 + threadIdx.x;
  if (i >= n4) return;
  float4 v = reinterpret_cast<const float4*>(in)[i];
  union { ushort4 u; __hip_bfloat16 h[4]; } cv;
  cv.h[0] = __float2bfloat16(v.x);
  cv.h[1] = __float2bfloat16(v.y);
  cv.h[2] = __float2bfloat16(v.z);
  cv.h[3] = __float2bfloat16(v.w);
  reinterpret_cast<ushort4*>(out)[i] = cv.u;
}

// out[n][k] = in[k][n] as bf16; zero-fill for n in [C, Cpad)
__global__ void transpose_f32_bf16(const float* __restrict__ in,
                                   __hip_bfloat16* __restrict__ out,
                                   int R, int C, int Cpad) {
  __shared__ float tile[32][33];
  int n0 = blockIdx.x * 32, k0 = blockIdx.y * 32;
  int tx = threadIdx.x, ty = threadIdx.y;  // (32,8)
#pragma unroll
  for (int j = 0; j < 32; j += 8) {
    int k = k0 + ty + j, n = n0 + tx;
    tile[ty + j][tx] = (n < C) ? in[(size_t)k * C + n] : 0.f;
  }
  __syncthreads();
#pragma unroll
  for (int j = 0; j < 32; j += 8) {
    int n = n0 + ty + j, k = k0 + tx;
    if (n < Cpad) out[(size_t)n * R + k] = __float2bfloat16(tile[tx][ty + j]);
  }
}

// ---------------- GEMM: C(MxN,f32) = A(MxK,bf16) * Bt(NxK,bf16)^T ----------------

__global__ __launch_bounds__(256, 2)
void gemm_bt_kernel(const __hip_bfloat16* __restrict__ A,
                    const __hip_bfloat16* __restrict__ Bt,
                    float* __restrict__ C,
                    int M, int N, int K, int NT) {
  __shared__ __hip_bfloat16 smA[128 * 32];
  __shared__ __hip_bfloat16 smB[128 * 32];
  const int bid = blockIdx.x;
  const int bm = (bid / NT) * 128;
  const int bn = (bid % NT) * 128;
  const int t = threadIdx.x;
  const int w = t >> 6, lane = t & 63;
  const int wr = (w >> 1) * 64, wc = (w & 1) * 64;

  f32x4 acc[4][4];
#pragma unroll
  for (int m = 0; m < 4; ++m)
#pragma unroll
    for (int n = 0; n < 4; ++n) acc[m][n] = (f32x4){0.f, 0.f, 0.f, 0.f};

  const int rl = lane >> 2;
  const int kof = (lane & 3) * 8;
  const size_t aBase0 = (size_t)(bm + w * 16 + rl) * K + kof;
  const size_t aBase1 = aBase0 + (size_t)64 * K;
  const size_t bBase0 = (size_t)(bn + w * 16 + rl) * K + kof;
  const size_t bBase1 = bBase0 + (size_t)64 * K;
  __hip_bfloat16* ldsA0 = smA + w * 512;
  __hip_bfloat16* ldsA1 = smA + w * 512 + 64 * 32;
  __hip_bfloat16* ldsB0 = smB + w * 512;
  __hip_bfloat16* ldsB1 = smB + w * 512 + 64 * 32;

  const int fr = lane & 15;
  const int fk = (lane >> 4) * 8;

  for (int k0 = 0; k0 < K; k0 += 32) {
    __builtin_amdgcn_global_load_lds((const __attribute__((address_space(1))) void*)(A + aBase0 + k0),
                                     (__attribute__((address_space(3))) void*)ldsA0, 16, 0, 0);
    __builtin_amdgcn_global_load_lds((const __attribute__((address_space(1))) void*)(A + aBase1 + k0),
                                     (__attribute__((address_space(3))) void*)ldsA1, 16, 0, 0);
    __builtin_amdgcn_global_load_lds((const __attribute__((address_space(1))) void*)(Bt + bBase0 + k0),
                                     (__attribute__((address_space(3))) void*)ldsB0, 16, 0, 0);
    __builtin_amdgcn_global_load_lds((const __attribute__((address_space(1))) void*)(Bt + bBase1 + k0),
                                     (__attribute__((address_space(3))) void*)ldsB1, 16, 0, 0);
    __syncthreads();
    bf16x8 af[4], bfv[4];
#pragma unroll
    for (int m = 0; m < 4; ++m)
      af[m] = *reinterpret_cast<const bf16x8*>(smA + (wr + m * 16 + fr) * 32 + fk);
#pragma unroll
    for (int n = 0; n < 4; ++n)
      bfv[n] = *reinterpret_cast<const bf16x8*>(smB + (wc + n * 16 + fr) * 32 + fk);
#pragma unroll
    for (int m = 0; m < 4; ++m)
#pragma unroll
      for (int n = 0; n < 4; ++n)
        acc[m][n] = __builtin_amdgcn_mfma_f32_16x16x32_bf16(af[m], bfv[n], acc[m][n], 0, 0, 0);
    __syncthreads();
  }

  const int r4 = (lane >> 4) * 4;
  const int cn = lane & 15;
#pragma unroll
  for (int m = 0; m < 4; ++m)
#pragma unroll
    for (int n = 0; n < 4; ++n) {
      int row = bm + wr + m * 16 + r4;
      int col = bn + wc + n * 16 + cn;
      float* cp = C + (size_t)row * N + col;
#pragma unroll
      for (int j = 0; j < 4; ++j) cp[(size_t)j * N] = acc[m][n][j];
    }
}

// ---------------- dt / decay precompute ----------------

__global__ void dtdecay_kernel(const float* __restrict__ zx, const float* __restrict__ dt_bias,
                               const float* __restrict__ A_log,
                               float* __restrict__ dtb, float* __restrict__ decb) {
  int idx = blockIdx.x * 256 + threadIdx.x;
  if (idx >= BATCH * LSEQ * NH) return;
  int h = idx & 31;
  int bl = idx >> 5;
  float v = zx[(size_t)bl * DPROJ_PAD + (DI + CONVD) + h] + dt_bias[h];
  float dt = (v > 20.f) ? v : log1pf(expf(v));
  float dec = expf(-expf(A_log[h]) * dt);
  dtb[idx] = dt;
  decb[idx] = dec;
}

// ---------------- causal depthwise conv + silu ----------------

__global__ void conv_silu_kernel(const float* __restrict__ zx, const float* __restrict__ cw,
                                 const float* __restrict__ cb, float* __restrict__ xbc) {
  int idx = blockIdx.x * 256 + threadIdx.x;
  if (idx >= BATCH * LSEQ * CONVD) return;
  int c = idx % CONVD;
  int bl = idx / CONVD;
  int l = bl % LSEQ;
  int b = bl / LSEQ;
  const float* src = zx + (size_t)b * LSEQ * DPROJ_PAD + DI + c;
  float acc = cb[c];
  float4 wv = *reinterpret_cast<const float4*>(cw + c * 4);
  if (l >= 3) acc += wv.x * src[(size_t)(l - 3) * DPROJ_PAD];
  if (l >= 2) acc += wv.y * src[(size_t)(l - 2) * DPROJ_PAD];
  if (l >= 1) acc += wv.z * src[(size_t)(l - 1) * DPROJ_PAD];
  acc += wv.w * src[(size_t)l * DPROJ_PAD];
  xbc[idx] = acc / (1.f + expf(-acc));
}

// ---------------- chunked scan, pass 1: local scans (batched staging) ----------------
// wg = (b,h,c); wave w owns p = w*16+(lane&15); ng = lane>>4 owns a 32-wide n slice.
// Per TB=8-step batch: stage B/C (TB x 256 f32), X (TB x 64), dec/dt (TB each) into
// LDS via global_load_lds; 2 barriers per batch instead of 1 per step.

__global__ __launch_bounds__(256)
void ssd_local_kernel(const float* __restrict__ xbc, const float* __restrict__ dtb,
                      const float* __restrict__ decb, const float* __restrict__ Dparm,
                      float* __restrict__ y, __hip_bfloat16* __restrict__ sbuf,
                      float* __restrict__ pbuf) {
  __shared__ __align__(16) float bc[TB * 256];
  __shared__ __align__(16) float xb[TB * 64];
  __shared__ float dd[2 * TB];
  int bid = blockIdx.x;
  int c = bid & (NCH - 1);
  int h = (bid >> 4) & 31;
  int b = bid >> 9;
  int tid = threadIdx.x;
  int w = tid >> 6, l = tid & 63;
  int pl = l & 15, ng = l >> 4;
  int p = w * 16 + pl;
  int t0 = c * QCH;
  int nbase = ng * 32;

  const float* xc = xbc + (size_t)b * LSEQ * CONVD;
  float Dh = Dparm[h];

  float hreg[32];
#pragma unroll
  for (int i = 0; i < 32; ++i) hreg[i] = 0.f;

  float pc = 1.f;
  for (int bb = 0; bb < QCH / TB; ++bb) {
    int tb0 = t0 + bb * TB;
    // ---- stage batch ----
    // B/C rows tb0..tb0+7: wave w covers rows w and 4+w
    {
      const float* s0 = xc + (size_t)(tb0 + w) * CONVD + DI + l * 4;
      __builtin_amdgcn_global_load_lds((const __attribute__((address_space(1))) void*)s0,
                                       (__attribute__((address_space(3))) void*)(bc + w * 256), 16, 0, 0);
      const float* s1 = xc + (size_t)(tb0 + 4 + w) * CONVD + DI + l * 4;
      __builtin_amdgcn_global_load_lds((const __attribute__((address_space(1))) void*)s1,
                                       (__attribute__((address_space(3))) void*)(bc + 1024 + w * 256), 16, 0, 0);
    }
    // X: waves 0,1; tt = w*4 + (l>>4), col4 = l&15
    if (w < 2) {
      const float* sx = xc + (size_t)(tb0 + w * 4 + (l >> 4)) * CONVD + h * HD + (l & 15) * 4;
      __builtin_amdgcn_global_load_lds((const __attribute__((address_space(1))) void*)sx,
                                       (__attribute__((address_space(3))) void*)(xb + w * 256), 16, 0, 0);
    }
    // dec/dt
    if (tid < 2 * TB) {
      int tt = tid & (TB - 1);
      const float* src = (tid < TB) ? decb : dtb;
      dd[tid] = src[((size_t)b * LSEQ + tb0 + tt) * NH + h];
    }
    __syncthreads();
    // ---- compute TB steps ----
#pragma unroll
    for (int tt = 0; tt < TB; ++tt) {
      float dec = dd[tt];
      float dts = dd[TB + tt];
      float xv = xb[tt * 64 + p];
      float s = dts * xv;
      float Bf[32], Cf[32];
#pragma unroll
      for (int j = 0; j < 8; ++j) {
        int off = nbase + (((j + 2 * ng) & 7) << 2);
        *reinterpret_cast<float4*>(&Bf[j * 4]) = *reinterpret_cast<const float4*>(&bc[tt * 256 + off]);
        *reinterpret_cast<float4*>(&Cf[j * 4]) = *reinterpret_cast<const float4*>(&bc[tt * 256 + 128 + off]);
      }
      float yv0 = 0.f, yv1 = 0.f, yv2 = 0.f, yv3 = 0.f;
#pragma unroll
      for (int j = 0; j < 8; ++j) {
        float h0 = fmaf(hreg[j * 4 + 0], dec, s * Bf[j * 4 + 0]);
        float h1 = fmaf(hreg[j * 4 + 1], dec, s * Bf[j * 4 + 1]);
        float h2 = fmaf(hreg[j * 4 + 2], dec, s * Bf[j * 4 + 2]);
        float h3 = fmaf(hreg[j * 4 + 3], dec, s * Bf[j * 4 + 3]);
        hreg[j * 4 + 0] = h0; hreg[j * 4 + 1] = h1;
        hreg[j * 4 + 2] = h2; hreg[j * 4 + 3] = h3;
        yv0 = fmaf(h0, Cf[j * 4 + 0], yv0);
        yv1 = fmaf(h1, Cf[j * 4 + 1], yv1);
        yv2 = fmaf(h2, Cf[j * 4 + 2], yv2);
        yv3 = fmaf(h3, Cf[j * 4 + 3], yv3);
      }
      float yv = (yv0 + yv1) + (yv2 + yv3);
      yv += __shfl_xor(yv, 16);
      yv += __shfl_xor(yv, 32);
      pc *= dec;
      if (ng == 0)
        y[((size_t)b * LSEQ + tb0 + tt) * DI + h * HD + p] = yv + Dh * xv;
    }
    __syncthreads();
  }
  // store local end-state at true (swizzled) n positions: layout sbuf[bid][n][p]
  __hip_bfloat16* sp = sbuf + (size_t)bid * 8192;
#pragma unroll
  for (int j = 0; j < 8; ++j) {
    int n4 = nbase + (((j + 2 * ng) & 7) << 2);
#pragma unroll
    for (int e = 0; e < 4; ++e)
      sp[(n4 + e) * 64 + p] = __float2bfloat16(hreg[j * 4 + e]);
  }
  if (tid == 0) pbuf[bid] = pc;
}

// ---------------- chunked scan, pass 2: propagate chunk states ----------------

__global__ void ssd_prop_kernel(__hip_bfloat16* __restrict__ sbuf,
                                const float* __restrict__ pbuf) {
  int idx = blockIdx.x * 256 + threadIdx.x;   // 64 * 8192
  int bh = idx >> 13;
  int e = idx & 8191;
  __hip_bfloat16* base = sbuf + (size_t)bh * NCH * 8192 + e;
  const float* pb = pbuf + bh * NCH;
  float hs = 0.f;
  for (int cc = 0; cc < NCH; ++cc) {
    float sc = __bfloat162float(base[(size_t)cc * 8192]);
    base[(size_t)cc * 8192] = __float2bfloat16(hs);
    hs = fmaf(hs, pb[cc], sc);
  }
}

// ---------------- chunked scan, pass 3: cross-chunk correction (batched) ----------------

__global__ __launch_bounds__(256)
void ssd_corr_kernel(const float* __restrict__ xbc, const float* __restrict__ decb,
                     const __hip_bfloat16* __restrict__ sbuf, float* __restrict__ y) {
  int bid = blockIdx.x;
  int c = bid & (NCH - 1);
  if (c == 0) return;  // h_start = 0, no correction (block-uniform exit)
  __shared__ __align__(16) float cs[TB * 128];
  __shared__ float ddc[TB];
  int h = (bid >> 4) & 31;
  int b = bid >> 9;
  int tid = threadIdx.x;
  int w = tid >> 6, l = tid & 63;
  int pl = l & 15, ng = l >> 4;
  int p = w * 16 + pl;
  int t0 = c * QCH;
  int nbase = ng * 32;

  const float* xc = xbc + (size_t)b * LSEQ * CONVD;
  const __hip_bfloat16* sp = sbuf + (size_t)bid * 8192;
  float hs[32];
#pragma unroll
  for (int j = 0; j < 8; ++j) {
    int n4 = nbase + (((j + 2 * ng) & 7) << 2);
#pragma unroll
    for (int e = 0; e < 4; ++e)
      hs[j * 4 + e] = __bfloat162float(sp[(n4 + e) * 64 + p]);
  }

  float cum = 1.f;
  for (int bb = 0; bb < QCH / TB; ++bb) {
    int tb0 = t0 + bb * TB;
    // stage C batch: tt = w*2 + (l>>5), col4 = l&31
    {
      const float* sc = xc + (size_t)(tb0 + w * 2 + (l >> 5)) * CONVD + DI + DSTATE + (l & 31) * 4;
      __builtin_amdgcn_global_load_lds((const __attribute__((address_space(1))) void*)sc,
                                       (__attribute__((address_space(3))) void*)(cs + w * 256), 16, 0, 0);
    }
    if (tid < TB)
      ddc[tid] = decb[((size_t)b * LSEQ + tb0 + tid) * NH + h];
    __syncthreads();
#pragma unroll
    for (int tt = 0; tt < TB; ++tt) {
      float dec = ddc[tt];
      cum *= dec;
      float Cf[32];
#pragma unroll
      for (int j = 0; j < 8; ++j) {
        int off = nbase + (((j + 2 * ng) & 7) << 2);
        *reinterpret_cast<float4*>(&Cf[j * 4]) = *reinterpret_cast<const float4*>(&cs[tt * 128 + off]);
      }
      float yv0 = 0.f, yv1 = 0.f, yv2 = 0.f, yv3 = 0.f;
#pragma unroll
      for (int j = 0; j < 8; ++j) {
        yv0 = fmaf(hs[j * 4 + 0], Cf[j * 4 + 0], yv0);
        yv1 = fmaf(hs[j * 4 + 1], Cf[j * 4 + 1], yv1);
        yv2 = fmaf(hs[j * 4 + 2], Cf[j * 4 + 2], yv2);
        yv3 = fmaf(hs[j * 4 + 3], Cf[j * 4 + 3], yv3);
      }
      float yv = (yv0 + yv1) + (yv2 + yv3);
      yv += __shfl_xor(yv, 16);
      yv += __shfl_xor(yv, 32);
      if (ng == 0) {
        size_t yi = ((size_t)b * LSEQ + tb0 + tt) * DI + h * HD + p;
        y[yi] += cum * yv;
      }
    }
    __syncthreads();
  }
}

// ---------------- gating + RMS norm -> bf16 ----------------

__global__ __launch_bounds__(256)
void gate_rms_kernel(const float* __restrict__ y, const float* __restrict__ zx,
                     const float* __restrict__ nw, __hip_bfloat16* __restrict__ g) {
  int row = blockIdx.x;
  int t = threadIdx.x;
  const float* yr = y + (size_t)row * DI;
  const float* zr = zx + (size_t)row * DPROJ_PAD;
  float v[8];
  float ss = 0.f;
#pragma unroll
  for (int j = 0; j < 8; ++j) {
    int c = j * 256 + t;
    float z = zr[c];
    float vv = yr[c] * (z / (1.f + expf(-z)));
    v[j] = vv;
    ss += vv * vv;
  }
#pragma unroll
  for (int off = 32; off; off >>= 1) ss += __shfl_down(ss, off);
  __shared__ float red[4];
  if ((t & 63) == 0) red[t >> 6] = ss;
  __syncthreads();
  float tot = red[0] + red[1] + red[2] + red[3];
  float rstd = rsqrtf(tot * (1.f / DI) + EPSV);
#pragma unroll
  for (int j = 0; j < 8; ++j) {
    int c = j * 256 + t;
    g[(size_t)row * DI + c] = __float2bfloat16(v[j] * rstd * nw[c]);
  }
}

// ---------------- final RMS + residual ----------------

__global__ __launch_bounds__(256)
void final_rms_add(const float* __restrict__ o1, const float* __restrict__ x,
                   float* __restrict__ out) {
  int row = blockIdx.x;
  int t = threadIdx.x;
  const float* orow = o1 + (size_t)row * DMODEL;
  float v[4];
  float ss = 0.f;
#pragma unroll
  for (int j = 0; j < 4; ++j) {
    int c = j * 256 + t;
    float o = orow[c];
    v[j] = o;
    ss += o * o;
  }
#pragma unroll
  for (int off = 32; off; off >>= 1) ss += __shfl_down(ss, off);
  __shared__ float red[4];
  if ((t & 63) == 0) red[t >> 6] = ss;
  __syncthreads();
  float tot = red[0] + red[1] + red[2] + red[3];
  float rstd = rsqrtf(tot * (1.f / DMODEL) + EPSV);
#pragma unroll
  for (int j = 0; j < 4; ++j) {
    int c = j * 256 + t;
    out[(size_t)row * DMODEL + c] = v[j] * rstd + x[(size_t)row * DMODEL + c];
  }
}

// ---------------- launch ----------------

extern "C" void kernel_launch(void* const* d_in, const int* in_sizes, int n_in,
                              void* d_out, int out_size, void* d_ws, size_t ws_size,
                              hipStream_t stream) {
  const float* x       = (const float*)d_in[0];
  const float* W_in    = (const float*)d_in[1];
  const float* conv_w  = (const float*)d_in[2];
  const float* conv_b  = (const float*)d_in[3];
  const float* dt_bias = (const float*)d_in[4];
  const float* A_log   = (const float*)d_in[5];
  const float* Dp      = (const float*)d_in[6];
  const float* norm_w  = (const float*)d_in[7];
  const float* W_out   = (const float*)d_in[8];
  float* out = (float*)d_out;

  float* zx   = (float*)d_ws;                 // 4096 x 4480
  float* xbc  = zx + (size_t)18350080;        // 4096 x 2304
  float* ybuf = xbc + (size_t)9437184;        // 4096 x 2048
  float* dtb  = ybuf + (size_t)8388608;       // 131072
  float* decb = dtb + (size_t)131072;         // 131072
  __hip_bfloat16* xbf   = (__hip_bfloat16*)(decb + 131072);  // 4096x1024
  __hip_bfloat16* wtin  = xbf + (size_t)4194304;             // 4480x1024
  __hip_bfloat16* wtout = wtin + (size_t)4587520;            // 1024x2048
  float* pbuf = (float*)(wtout + (size_t)2097152);           // 1024 floats
  __hip_bfloat16* sbuf = xbf;  // overlay: xbf/wtin dead after GEMM1
  __hip_bfloat16* gbf = xbf;   // overlay: sbuf dead after ssd_corr
  float* o1 = xbc;             // overlay: xbc dead after ssd_corr

  f32_to_bf16_kernel<<<4096, 256, 0, stream>>>(x, xbf, 1048576);
  transpose_f32_bf16<<<dim3(140, 32), dim3(32, 8), 0, stream>>>(W_in, wtin, 1024, 4384, 4480);
  transpose_f32_bf16<<<dim3(32, 64), dim3(32, 8), 0, stream>>>(W_out, wtout, 2048, 1024, 1024);

  gemm_bt_kernel<<<1120, 256, 0, stream>>>(xbf, wtin, zx, 4096, 4480, 1024, 35);

  dtdecay_kernel<<<512, 256, 0, stream>>>(zx, dt_bias, A_log, dtb, decb);
  conv_silu_kernel<<<36864, 256, 0, stream>>>(zx, conv_w, conv_b, xbc);

  ssd_local_kernel<<<1024, 256, 0, stream>>>(xbc, dtb, decb, Dp, ybuf, sbuf, pbuf);
  ssd_prop_kernel<<<2048, 256, 0, stream>>>(sbuf, pbuf);
  ssd_corr_kernel<<<1024, 256, 0, stream>>>(xbc, decb, sbuf, ybuf);

  gate_rms_kernel<<<4096, 256, 0, stream>>>(ybuf, zx, norm_w, gbf);

  gemm_bt_kernel<<<256, 256, 0, stream>>>(gbf, wtout, o1, 4096, 1024, 2048, 8);

  final_rms_add<<<4096, 256, 0, stream>>>(o1, x, out);
}